// Round 6
// baseline (342.629 us; speedup 1.0000x reference)
//
#include <hip/hip_runtime.h>
#include <hip/hip_bf16.h>

#define NN 768
#define MD 1024
#define NPAIR 295296            // 768*769/2
#define NPBLK 1154              // ceil(NPAIR/256)

typedef __attribute__((ext_vector_type(8))) short s16x8;
typedef __attribute__((ext_vector_type(4))) float f32x4;
typedef __attribute__((ext_vector_type(2))) __bf16 b16x2;

__device__ __forceinline__ ushort bf16_rn(float f) {
    uint u = __builtin_bit_cast(uint, f);
    u += 0x7FFFu + ((u >> 16) & 1u);
    return (ushort)(u >> 16);
}

// inverse triangular index: p -> (i,j), off(i) = i*(1537-i)/2, j = i + p - off(i)
__device__ __forceinline__ void ptoij(int p, int& io, int& jo) {
    const float disc = (float)(1537 * 1537 - 8 * p);
    int i = (int)((1537.0f - sqrtf(disc)) * 0.5f);
    i = i < 0 ? 0 : (i > 767 ? 767 : i);
    while (i > 0 && p < i * (1537 - i) / 2) --i;
    while (i < 767 && p >= (i + 1) * (1536 - i) / 2) ++i;
    io = i;
    jo = i + (p - i * (1537 - i) / 2);
}

#define GLOAD16(gsrc, ldst)                                                        \
    __builtin_amdgcn_global_load_lds(                                              \
        (const __attribute__((address_space(1))) void*)(gsrc),                     \
        (__attribute__((address_space(3))) void*)(ldst), 16, 0, 0)

// ---------- one-time: W2 -> bf16 (RNE), chunk-major + XOR-swizzled -------------
// chunk c (m0=c*64): 128 rows(k) x 128B; byte-in-row = (mloc8*16) ^ ((k&7)<<4)
__global__ __launch_bounds__(256) void w2bf16(const float* __restrict__ W2,
                                              ushort* __restrict__ WhiS)
{
    const int id = blockIdx.x * 256 + threadIdx.x;   // 16384 = 128 k * 128 groups
    const int k = id >> 7;
    const int m = (id & 127) * 8;
    const float4 a = *reinterpret_cast<const float4*>(W2 + k * MD + m);
    const float4 b = *reinterpret_cast<const float4*>(W2 + k * MD + m + 4);
    const float w[8] = {a.x, a.y, a.z, a.w, b.x, b.y, b.z, b.w};
    s16x8 h;
#pragma unroll
    for (int e = 0; e < 8; ++e) h[e] = (short)bf16_rn(w[e]);
    const int c = m >> 6;
    const int mloc8 = (m >> 3) & 7;
    const int byte = (mloc8 * 16) ^ ((k & 7) << 4);
    const int off = c * 8192 + ((k * 128 + byte) >> 1);
    *reinterpret_cast<s16x8*>(&WhiS[off]) = h;
}

// ---------- one-time: factorized exponential tables ----------------------------
// EA[i][m] = 2^(-(a_m x_i + b_m) log2e), EC[j][m] = 2^(-c_m x_j log2e)
// sigma(z_ijm) = 1 / (1 + EA[i][m]*EC[j][m])
__global__ __launch_bounds__(256) void etab(const float* __restrict__ x,
                                            const float* __restrict__ W1,
                                            const float* __restrict__ b1,
                                            float* __restrict__ EA,
                                            float* __restrict__ EC)
{
    const int i = blockIdx.x;
    const float xi = x[i];
    const float NL2E = -1.4426950408889634f;
    for (int m = threadIdx.x; m < MD; m += 256) {
        const float2 w = reinterpret_cast<const float2*>(W1)[m];
        EA[i * MD + m] = __builtin_amdgcn_exp2f(fmaf(w.x, xi, b1[m]) * NL2E);
        EC[i * MD + m] = __builtin_amdgcn_exp2f(w.y * xi * NL2E);
    }
}

// ---- macros (use ambient locals) ----------------------------------------------
#define STAGE(cc, buf)                                                       \
    {                                                                        \
        const ushort* sh_ = WhiS + (cc) * 8192;                              \
        _Pragma("unroll")                                                    \
        for (int q_ = 0; q_ < 4; ++q_) {                                     \
            const int off_ = (wv * 4 + q_) * 512;                            \
            GLOAD16(sh_ + off_ + lane * 8, &Wh[buf][off_]);                  \
        }                                                                    \
    }

// sigma = rcp(1 + EA*EC) from tables; no transcendental exp
#define SIG_CHUNK2(cc, dst)                                                  \
    {                                                                        \
        _Pragma("unroll")                                                    \
        for (int ks_ = 0; ks_ < 2; ++ks_) {                                  \
            const int mo_ = (cc) * 64 + ks_ * 32;                            \
            _Pragma("unroll")                                                \
            for (int tm_ = 0; tm_ < 4; ++tm_) {                              \
                const float* pa_ = pEA[tm_] + mo_;                           \
                const float* pc_ = pEC[tm_] + mo_;                           \
                const f32x4 ea0_ = *reinterpret_cast<const f32x4*>(pa_);     \
                const f32x4 ea1_ = *reinterpret_cast<const f32x4*>(pa_ + 4); \
                const f32x4 ec0_ = *reinterpret_cast<const f32x4*>(pc_);     \
                const f32x4 ec1_ = *reinterpret_cast<const f32x4*>(pc_ + 4); \
                float s_[8];                                                 \
                _Pragma("unroll")                                            \
                for (int e_ = 0; e_ < 4; ++e_) {                             \
                    s_[e_]     = __builtin_amdgcn_rcpf(fmaf(ea0_[e_], ec0_[e_], 1.0f)); \
                    s_[e_ + 4] = __builtin_amdgcn_rcpf(fmaf(ea1_[e_], ec1_[e_], 1.0f)); \
                }                                                            \
                union { s16x8 v; uint u[4]; } fr_;                           \
                _Pragma("unroll")                                            \
                for (int h_ = 0; h_ < 4; ++h_) {                             \
                    b16x2 p_;                                                \
                    p_.x = (__bf16)s_[2 * h_];                               \
                    p_.y = (__bf16)s_[2 * h_ + 1];                           \
                    fr_.u[h_] = __builtin_bit_cast(uint, p_);                \
                }                                                            \
                dst[ks_][tm_] = fr_.v;                                       \
            }                                                                \
        }                                                                    \
    }

#define MFMA_STEP(buf, src)                                                  \
    {                                                                        \
        _Pragma("unroll")                                                    \
        for (int ks_ = 0; ks_ < 2; ++ks_) {                                  \
            _Pragma("unroll")                                                \
            for (int th_ = 0; th_ < 2; ++th_) {                              \
                s16x8 bh_[4];                                                \
                _Pragma("unroll")                                            \
                for (int tn_ = 0; tn_ < 4; ++tn_) {                          \
                    const int k_ = th_ * 64 + tn_ * 16 + l15;                \
                    const int byte_ = (ks_ * 64 + l4 * 16) ^ ((k_ & 7) << 4);\
                    const int idx_ = (k_ * 128 + byte_) >> 1;                \
                    bh_[tn_] = *reinterpret_cast<const s16x8*>(&Wh[buf][idx_]); \
                }                                                            \
                __builtin_amdgcn_s_setprio(1);                               \
                _Pragma("unroll")                                            \
                for (int tm_ = 0; tm_ < 4; ++tm_)                            \
                    _Pragma("unroll")                                        \
                    for (int tn_ = 0; tn_ < 4; ++tn_)                        \
                        acc[tm_][th_][tn_] = __builtin_amdgcn_mfma_f32_16x16x32_bf16( \
                            src[ks_][tm_], bh_[tn_], acc[tm_][th_][tn_], 0, 0, 0);    \
                __builtin_amdgcn_s_setprio(0);                               \
            }                                                                \
        }                                                                    \
    }

// weights in sa/sc/sb are pre-scaled by -log2(e) (R5 fallback path)
#define SIG_CHUNK(cc, dst)                                                   \
    {                                                                        \
        _Pragma("unroll")                                                    \
        for (int ks_ = 0; ks_ < 2; ++ks_) {                                  \
            const int m0_ = (cc) * 64 + ks_ * 32 + l4 * 8;                   \
            const f32x4 a0_ = *reinterpret_cast<const f32x4*>(&sa[m0_]);     \
            const f32x4 a1_ = *reinterpret_cast<const f32x4*>(&sa[m0_ + 4]); \
            const f32x4 c0_ = *reinterpret_cast<const f32x4*>(&sc[m0_]);     \
            const f32x4 c1_ = *reinterpret_cast<const f32x4*>(&sc[m0_ + 4]); \
            const f32x4 b0_ = *reinterpret_cast<const f32x4*>(&sb[m0_]);     \
            const f32x4 b1_ = *reinterpret_cast<const f32x4*>(&sb[m0_ + 4]); \
            _Pragma("unroll")                                                \
            for (int tm_ = 0; tm_ < 4; ++tm_) {                              \
                float s_[8];                                                 \
                _Pragma("unroll")                                            \
                for (int e_ = 0; e_ < 4; ++e_) {                             \
                    const float u0_ = fmaf(xia[tm_], a0_[e_], fmaf(xja[tm_], c0_[e_], b0_[e_])); \
                    const float u1_ = fmaf(xia[tm_], a1_[e_], fmaf(xja[tm_], c1_[e_], b1_[e_])); \
                    s_[e_]     = __builtin_amdgcn_rcpf(1.0f + __builtin_amdgcn_exp2f(u0_)); \
                    s_[e_ + 4] = __builtin_amdgcn_rcpf(1.0f + __builtin_amdgcn_exp2f(u1_)); \
                }                                                            \
                union { s16x8 v; uint u[4]; } fr_;                           \
                _Pragma("unroll")                                            \
                for (int h_ = 0; h_ < 4; ++h_) {                             \
                    b16x2 p_;                                                \
                    p_.x = (__bf16)s_[2 * h_];                               \
                    p_.y = (__bf16)s_[2 * h_ + 1];                           \
                    fr_.u[h_] = __builtin_bit_cast(uint, p_);                \
                }                                                            \
                dst[ks_][tm_] = fr_.v;                                       \
            }                                                                \
        }                                                                    \
    }

// ---------- main v2: table-driven sigmoid (no exp2 in hot loop) ----------------
__global__ __launch_bounds__(256, 2) void mlp_pairs2(
    const float* __restrict__ EA, const float* __restrict__ EC,
    const ushort* __restrict__ WhiS,
    const float* __restrict__ b2, const float* __restrict__ W3,
    const float* __restrict__ b3, float* __restrict__ K)
{
    __shared__ __align__(16) ushort Wh[2][8192];

    const int t = threadIdx.x;
    const int lane = t & 63, wv = t >> 6;
    const int l15 = lane & 15, l4 = lane >> 4;

    const int pairbase = blockIdx.x * 256 + wv * 64;

    // per-lane table base pointers for the 4 A-frag rows (m-offset l4*8 folded in)
    const float* pEA[4];
    const float* pEC[4];
#pragma unroll
    for (int tm = 0; tm < 4; ++tm) {
        int p = pairbase + tm * 16 + l15;
        if (p >= NPAIR) p = 0;
        int i, j;
        ptoij(p, i, j);
        pEA[tm] = EA + i * MD + l4 * 8;
        pEC[tm] = EC + j * MD + l4 * 8;
    }

    f32x4 acc[4][2][4];
#pragma unroll
    for (int a = 0; a < 4; ++a)
#pragma unroll
        for (int th = 0; th < 2; ++th)
#pragma unroll
            for (int b = 0; b < 4; ++b) acc[a][th][b] = (f32x4){0.f, 0.f, 0.f, 0.f};

    STAGE(0, 0);
    __syncthreads();                 // Wh[0] staged (barrier drains vmcnt)

    s16x8 ah[2][4];
    for (int c = 0; c < 16; ++c) {
        if (c < 15) STAGE(c + 1, (c + 1) & 1);   // async into other buffer
        SIG_CHUNK2(c, ah);                       // table loads + fma/rcp
        MFMA_STEP(c & 1, ah);
        __syncthreads();
    }

    // epilogue: v = sum_k W3[k]*relu(h2 + b2[k]) + b3; reduce over 16 lanes (k)
    float w3v[2][4], b2v[2][4];
#pragma unroll
    for (int th = 0; th < 2; ++th)
#pragma unroll
        for (int tn = 0; tn < 4; ++tn) {
            const int k = th * 64 + tn * 16 + l15;
            w3v[th][tn] = W3[k];
            b2v[th][tn] = b2[k];
        }
    const float b3v = b3[0];
#pragma unroll
    for (int tm = 0; tm < 4; ++tm)
#pragma unroll
        for (int r = 0; r < 4; ++r) {
            float v = 0.f;
#pragma unroll
            for (int th = 0; th < 2; ++th)
#pragma unroll
                for (int tn = 0; tn < 4; ++tn)
                    v = fmaf(w3v[th][tn], fmaxf(acc[tm][th][tn][r] + b2v[th][tn], 0.f), v);
            v += __shfl_xor(v, 1, 16);
            v += __shfl_xor(v, 2, 16);
            v += __shfl_xor(v, 4, 16);
            v += __shfl_xor(v, 8, 16);
            if (l15 == 0) {
                const int p = pairbase + tm * 16 + l4 * 4 + r;
                if (p < NPAIR) {
                    int i, j;
                    ptoij(p, i, j);
                    K[i * NN + j] = v + b3v;
                }
            }
        }
}

// ---------- fallback (R5 proven): in-loop exp2 sigmoid -------------------------
__global__ __launch_bounds__(256, 2) void mlp_pairs(
    const float* __restrict__ x,
    const float* __restrict__ W1, const float* __restrict__ b1,
    const ushort* __restrict__ WhiS,
    const float* __restrict__ b2, const float* __restrict__ W3,
    const float* __restrict__ b3, float* __restrict__ K)
{
    __shared__ __align__(16) float sa[MD], sc[MD], sb[MD];
    __shared__ __align__(16) ushort Wh[2][8192];

    const int t = threadIdx.x;
    const int lane = t & 63, wv = t >> 6;
    const int l15 = lane & 15, l4 = lane >> 4;

    const float NL2E = -1.4426950408889634f;
    for (int m = t; m < MD; m += 256) {
        const float2 w = reinterpret_cast<const float2*>(W1)[m];
        sa[m] = w.x * NL2E;
        sc[m] = w.y * NL2E;
        sb[m] = b1[m] * NL2E;
    }

    const int pairbase = blockIdx.x * 256 + wv * 64;

    float xia[4], xja[4];
#pragma unroll
    for (int tm = 0; tm < 4; ++tm) {
        const int p = pairbase + tm * 16 + l15;
        if (p < NPAIR) {
            int i, j;
            ptoij(p, i, j);
            xia[tm] = x[i];
            xja[tm] = x[j];
        } else {
            xia[tm] = 0.f;
            xja[tm] = 0.f;
        }
    }

    f32x4 acc[4][2][4];
#pragma unroll
    for (int a = 0; a < 4; ++a)
#pragma unroll
        for (int th = 0; th < 2; ++th)
#pragma unroll
            for (int b = 0; b < 4; ++b) acc[a][th][b] = (f32x4){0.f, 0.f, 0.f, 0.f};

    STAGE(0, 0);
    __syncthreads();

    s16x8 ah[2][4];
    for (int c = 0; c < 16; ++c) {
        if (c < 15) STAGE(c + 1, (c + 1) & 1);
        SIG_CHUNK(c, ah);
        MFMA_STEP(c & 1, ah);
        __syncthreads();
    }

    float w3v[2][4], b2v[2][4];
#pragma unroll
    for (int th = 0; th < 2; ++th)
#pragma unroll
        for (int tn = 0; tn < 4; ++tn) {
            const int k = th * 64 + tn * 16 + l15;
            w3v[th][tn] = W3[k];
            b2v[th][tn] = b2[k];
        }
    const float b3v = b3[0];
#pragma unroll
    for (int tm = 0; tm < 4; ++tm)
#pragma unroll
        for (int r = 0; r < 4; ++r) {
            float v = 0.f;
#pragma unroll
            for (int th = 0; th < 2; ++th)
#pragma unroll
                for (int tn = 0; tn < 4; ++tn)
                    v = fmaf(w3v[th][tn], fmaxf(acc[tm][th][tn][r] + b2v[th][tn], 0.f), v);
            v += __shfl_xor(v, 1, 16);
            v += __shfl_xor(v, 2, 16);
            v += __shfl_xor(v, 4, 16);
            v += __shfl_xor(v, 8, 16);
            if (l15 == 0) {
                const int p = pairbase + tm * 16 + l4 * 4 + r;
                if (p < NPAIR) {
                    int i, j;
                    ptoij(p, i, j);
                    K[i * NN + j] = v + b3v;
                }
            }
        }
}

// ---------------- Kernel 2: C = K^T K (768^3 fp32 GEMM) --------------------
__global__ __launch_bounds__(256) void ktk(const float* __restrict__ K,
                                           float* __restrict__ C)
{
    const int b0 = blockIdx.x * 64;
    const int a0 = blockIdx.y * 64;
    __shared__ float Ka[64][68];
    __shared__ float Kb[64][68];
    const int t  = threadIdx.x;
    const int tb = t & 15;
    const int ta = t >> 4;
    float acc[4][4];
#pragma unroll
    for (int u = 0; u < 4; u++)
#pragma unroll
        for (int v = 0; v < 4; v++) acc[u][v] = 0.f;
    const int kmax = (a0 < b0 ? a0 : b0) + 64;
    for (int k0 = 0; k0 < kmax; k0 += 64) {
#pragma unroll
        for (int q = 0; q < 4; q++) {
            const int f  = t + q * 256;
            const int kk = f >> 4;
            const int c4 = (f & 15) * 4;
            *reinterpret_cast<float4*>(&Ka[kk][c4]) =
                *reinterpret_cast<const float4*>(K + (k0 + kk) * NN + a0 + c4);
            *reinterpret_cast<float4*>(&Kb[kk][c4]) =
                *reinterpret_cast<const float4*>(K + (k0 + kk) * NN + b0 + c4);
        }
        __syncthreads();
#pragma unroll 8
        for (int kk = 0; kk < 64; kk++) {
            const float4 av = *reinterpret_cast<const float4*>(&Ka[kk][ta * 4]);
            const float4 bv = *reinterpret_cast<const float4*>(&Kb[kk][tb * 4]);
            const float a4[4] = {av.x, av.y, av.z, av.w};
            const float b4[4] = {bv.x, bv.y, bv.z, bv.w};
#pragma unroll
            for (int u = 0; u < 4; u++)
#pragma unroll
                for (int v = 0; v < 4; v++)
                    acc[u][v] = fmaf(a4[u], b4[v], acc[u][v]);
        }
        __syncthreads();
    }
#pragma unroll
    for (int u = 0; u < 4; u++) {
        float4 o;
        o.x = acc[u][0]; o.y = acc[u][1]; o.z = acc[u][2]; o.w = acc[u][3];
        *reinterpret_cast<float4*>(C + (a0 + ta * 4 + u) * NN + b0 + tb * 4) = o;
    }
}

extern "C" void kernel_launch(void* const* d_in, const int* in_sizes, int n_in,
                              void* d_out, int out_size, void* d_ws, size_t ws_size,
                              hipStream_t stream)
{
    const float* x  = (const float*)d_in[0];
    const float* W1 = (const float*)d_in[1];
    const float* b1 = (const float*)d_in[2];
    const float* W2 = (const float*)d_in[3];
    const float* b2 = (const float*)d_in[4];
    const float* W3 = (const float*)d_in[5];
    const float* b3 = (const float*)d_in[6];
    float* Kmat = (float*)d_ws;                       // 2,359,296 B
    float* C    = (float*)d_out;

    const size_t kBytes  = (size_t)NN * NN * sizeof(float);
    const size_t wBytes  = 262144;                    // W2 bf16 swizzled
    const size_t tBytes  = (size_t)NN * MD * sizeof(float);   // 3 MB per table
    const size_t needTab = kBytes + wBytes + 2 * tBytes;      // ~8.9 MB
    const size_t needR5  = kBytes + wBytes;                   // ~2.6 MB

    hipMemsetAsync(Kmat, 0, kBytes, stream);
    if (ws_size >= needTab) {
        ushort* WhiS = (ushort*)((char*)d_ws + kBytes);
        float*  EA   = (float*)((char*)d_ws + kBytes + wBytes);
        float*  EC   = EA + NN * MD;
        w2bf16<<<64, 256, 0, stream>>>(W2, WhiS);
        etab<<<NN, 256, 0, stream>>>(x, W1, b1, EA, EC);
        mlp_pairs2<<<NPBLK, 256, 0, stream>>>(EA, EC, WhiS, b2, W3, b3, Kmat);
    } else if (ws_size >= needR5) {
        ushort* WhiS = (ushort*)((char*)d_ws + kBytes);
        w2bf16<<<64, 256, 0, stream>>>(W2, WhiS);
        mlp_pairs<<<NPBLK, 256, 0, stream>>>(x, W1, b1, WhiS, b2, W3, b3, Kmat);
    }
    ktk<<<dim3(NN / 64, NN / 64), 256, 0, stream>>>(Kmat, C);
}

// Round 7
// 327.860 us; speedup vs baseline: 1.0450x; 1.0450x over previous
//
#include <hip/hip_runtime.h>
#include <hip/hip_bf16.h>

#define NN 768
#define MD 1024
#define NPAIR 295296            // 768*769/2
#define NPBLK 1154              // ceil(NPAIR/256)

typedef __attribute__((ext_vector_type(8))) short s16x8;
typedef __attribute__((ext_vector_type(4))) float f32x4;
typedef __attribute__((ext_vector_type(2))) __bf16 b16x2;

__device__ __forceinline__ ushort bf16_rn(float f) {
    uint u = __builtin_bit_cast(uint, f);
    u += 0x7FFFu + ((u >> 16) & 1u);
    return (ushort)(u >> 16);
}

// inverse triangular index: p -> (i,j), off(i) = i*(1537-i)/2, j = i + p - off(i)
__device__ __forceinline__ void ptoij(int p, int& io, int& jo) {
    const float disc = (float)(1537 * 1537 - 8 * p);
    int i = (int)((1537.0f - sqrtf(disc)) * 0.5f);
    i = i < 0 ? 0 : (i > 767 ? 767 : i);
    while (i > 0 && p < i * (1537 - i) / 2) --i;
    while (i < 767 && p >= (i + 1) * (1536 - i) / 2) ++i;
    io = i;
    jo = i + (p - i * (1537 - i) / 2);
}

#define GLOAD16(gsrc, ldst)                                                        \
    __builtin_amdgcn_global_load_lds(                                              \
        (const __attribute__((address_space(1))) void*)(gsrc),                     \
        (__attribute__((address_space(3))) void*)(ldst), 16, 0, 0)

// ---------- one-time: W2 -> bf16 (RNE), chunk-major + XOR-swizzled -------------
__global__ __launch_bounds__(256) void w2bf16(const float* __restrict__ W2,
                                              ushort* __restrict__ WhiS)
{
    const int id = blockIdx.x * 256 + threadIdx.x;
    const int k = id >> 7;
    const int m = (id & 127) * 8;
    const float4 a = *reinterpret_cast<const float4*>(W2 + k * MD + m);
    const float4 b = *reinterpret_cast<const float4*>(W2 + k * MD + m + 4);
    const float w[8] = {a.x, a.y, a.z, a.w, b.x, b.y, b.z, b.w};
    s16x8 h;
#pragma unroll
    for (int e = 0; e < 8; ++e) h[e] = (short)bf16_rn(w[e]);
    const int c = m >> 6;
    const int mloc8 = (m >> 3) & 7;
    const int byte = (mloc8 * 16) ^ ((k & 7) << 4);
    const int off = c * 8192 + ((k * 128 + byte) >> 1);
    *reinterpret_cast<s16x8*>(&WhiS[off]) = h;
}

// ---------- one-time: factorized exponential tables ----------------------------
// EA[i][m] = 2^(-(a_m x_i + b_m) log2e), EC[j][m] = 2^(-c_m x_j log2e)
// sigma(z_ijm) = 1 / (1 + EA[i][m]*EC[j][m])
__global__ __launch_bounds__(256) void etab(const float* __restrict__ x,
                                            const float* __restrict__ W1,
                                            const float* __restrict__ b1,
                                            float* __restrict__ EA,
                                            float* __restrict__ EC)
{
    const int i = blockIdx.x;
    const float xi = x[i];
    const float NL2E = -1.4426950408889634f;
    for (int m = threadIdx.x; m < MD; m += 256) {
        const float2 w = reinterpret_cast<const float2*>(W1)[m];
        EA[i * MD + m] = __builtin_amdgcn_exp2f(fmaf(w.x, xi, b1[m]) * NL2E);
        EC[i * MD + m] = __builtin_amdgcn_exp2f(w.y * xi * NL2E);
    }
}

// ---- shared macros (ambient locals) --------------------------------------------
#define STAGE(cc, buf)                                                       \
    {                                                                        \
        const ushort* sh_ = WhiS + (cc) * 8192;                              \
        _Pragma("unroll")                                                    \
        for (int q_ = 0; q_ < 4; ++q_) {                                     \
            const int off_ = (wv * 4 + q_) * 512;                            \
            GLOAD16(sh_ + off_ + lane * 8, &Wh[buf][off_]);                  \
        }                                                                    \
    }

#define MFMA_STEP(buf, src)                                                  \
    {                                                                        \
        _Pragma("unroll")                                                    \
        for (int ks_ = 0; ks_ < 2; ++ks_) {                                  \
            _Pragma("unroll")                                                \
            for (int th_ = 0; th_ < 2; ++th_) {                              \
                s16x8 bh_[4];                                                \
                _Pragma("unroll")                                            \
                for (int tn_ = 0; tn_ < 4; ++tn_) {                          \
                    const int k_ = th_ * 64 + tn_ * 16 + l15;                \
                    const int byte_ = (ks_ * 64 + l4 * 16) ^ ((k_ & 7) << 4);\
                    const int idx_ = (k_ * 128 + byte_) >> 1;                \
                    bh_[tn_] = *reinterpret_cast<const s16x8*>(&Wh[buf][idx_]); \
                }                                                            \
                __builtin_amdgcn_s_setprio(1);                               \
                _Pragma("unroll")                                            \
                for (int tm_ = 0; tm_ < 4; ++tm_)                            \
                    _Pragma("unroll")                                        \
                    for (int tn_ = 0; tn_ < 4; ++tn_)                        \
                        acc[tm_][th_][tn_] = __builtin_amdgcn_mfma_f32_16x16x32_bf16( \
                            src[ks_][tm_], bh_[tn_], acc[tm_][th_][tn_], 0, 0, 0);    \
                __builtin_amdgcn_s_setprio(0);                               \
            }                                                                \
        }                                                                    \
    }

// ---- table-version macros ------------------------------------------------------
// issue EC prefetch for group (cc, ks, tp) into named buffer b0..b3
#define LOADC(cc, ks, tp, b0, b1, b2, b3)                                    \
    {                                                                        \
        const uint base0_ = offC[2 * (tp)]     + (cc) * 64 + (ks) * 32;      \
        const uint base1_ = offC[2 * (tp) + 1] + (cc) * 64 + (ks) * 32;      \
        b0 = *reinterpret_cast<const f32x4*>(EC + base0_);                   \
        b1 = *reinterpret_cast<const f32x4*>(EC + base0_ + 4);               \
        b2 = *reinterpret_cast<const f32x4*>(EC + base1_);                   \
        b3 = *reinterpret_cast<const f32x4*>(EC + base1_ + 4);               \
    }

// compute 2 A-frags (ks, tm=2tp,2tp+1) from prefetched EC + at-use EA
#define COMPG(cc, ks, tp, b0, b1, b2, b3)                                    \
    {                                                                        \
        const f32x4 one4_ = (f32x4){1.f, 1.f, 1.f, 1.f};                     \
        const uint a0b_ = offA[2 * (tp)]     + (cc) * 64 + (ks) * 32;        \
        const uint a1b_ = offA[2 * (tp) + 1] + (cc) * 64 + (ks) * 32;        \
        const f32x4 ea00_ = *reinterpret_cast<const f32x4*>(EA + a0b_);      \
        const f32x4 ea01_ = *reinterpret_cast<const f32x4*>(EA + a0b_ + 4);  \
        const f32x4 ea10_ = *reinterpret_cast<const f32x4*>(EA + a1b_);      \
        const f32x4 ea11_ = *reinterpret_cast<const f32x4*>(EA + a1b_ + 4);  \
        const f32x4 t00_ = __builtin_elementwise_fma(ea00_, b0, one4_);      \
        const f32x4 t01_ = __builtin_elementwise_fma(ea01_, b1, one4_);      \
        const f32x4 t10_ = __builtin_elementwise_fma(ea10_, b2, one4_);      \
        const f32x4 t11_ = __builtin_elementwise_fma(ea11_, b3, one4_);      \
        union { s16x8 v; uint u[4]; } f0_, f1_;                              \
        _Pragma("unroll")                                                    \
        for (int h_ = 0; h_ < 2; ++h_) {                                     \
            b16x2 p0_, p1_, p2_, p3_;                                        \
            p0_.x = (__bf16)__builtin_amdgcn_rcpf(t00_[2 * h_]);             \
            p0_.y = (__bf16)__builtin_amdgcn_rcpf(t00_[2 * h_ + 1]);         \
            p1_.x = (__bf16)__builtin_amdgcn_rcpf(t01_[2 * h_]);             \
            p1_.y = (__bf16)__builtin_amdgcn_rcpf(t01_[2 * h_ + 1]);         \
            p2_.x = (__bf16)__builtin_amdgcn_rcpf(t10_[2 * h_]);             \
            p2_.y = (__bf16)__builtin_amdgcn_rcpf(t10_[2 * h_ + 1]);         \
            p3_.x = (__bf16)__builtin_amdgcn_rcpf(t11_[2 * h_]);             \
            p3_.y = (__bf16)__builtin_amdgcn_rcpf(t11_[2 * h_ + 1]);         \
            f0_.u[h_]     = __builtin_bit_cast(uint, p0_);                   \
            f0_.u[h_ + 2] = __builtin_bit_cast(uint, p1_);                   \
            f1_.u[h_]     = __builtin_bit_cast(uint, p2_);                   \
            f1_.u[h_ + 2] = __builtin_bit_cast(uint, p3_);                   \
        }                                                                    \
        ah[ks][2 * (tp)]     = f0_.v;                                        \
        ah[ks][2 * (tp) + 1] = f1_.v;                                        \
    }

// ---------- main v3: tables + rolling register prefetch ------------------------
__global__ __launch_bounds__(256, 2) void mlp_pairs3(
    const float* __restrict__ EA, const float* __restrict__ EC,
    const ushort* __restrict__ WhiS,
    const float* __restrict__ b2, const float* __restrict__ W3,
    const float* __restrict__ b3, float* __restrict__ K)
{
    __shared__ __align__(16) ushort Wh[2][8192];

    const int t = threadIdx.x;
    const int lane = t & 63, wv = t >> 6;
    const int l15 = lane & 15, l4 = lane >> 4;

    const int pairbase = blockIdx.x * 256 + wv * 64;

    // element offsets of each A-frag row's table slice (l4*8 folded in)
    uint offA[4], offC[4];
#pragma unroll
    for (int tm = 0; tm < 4; ++tm) {
        int p = pairbase + tm * 16 + l15;
        if (p >= NPAIR) p = 0;
        int i, j;
        ptoij(p, i, j);
        offA[tm] = (uint)(i * MD + l4 * 8);
        offC[tm] = (uint)(j * MD + l4 * 8);
    }

    f32x4 acc[4][2][4];
#pragma unroll
    for (int a = 0; a < 4; ++a)
#pragma unroll
        for (int th = 0; th < 2; ++th)
#pragma unroll
            for (int b = 0; b < 4; ++b) acc[a][th][b] = (f32x4){0.f, 0.f, 0.f, 0.f};

    f32x4 bA0, bA1, bA2, bA3;    // rolling EC prefetch buffers
    f32x4 bB0, bB1, bB2, bB3;

    STAGE(0, 0);
    LOADC(0, 0, 0, bA0, bA1, bA2, bA3);      // prologue: G0 of chunk 0
    __syncthreads();                          // Wh[0] staged

    s16x8 ah[2][4];
    for (int c = 0; c < 16; ++c) {
        if (c < 15) STAGE(c + 1, (c + 1) & 1);
        // G0: consume A (ks0,tp0), prefetch G1 -> B
        LOADC(c, 0, 1, bB0, bB1, bB2, bB3);
        COMPG(c, 0, 0, bA0, bA1, bA2, bA3);
        // G1: consume B (ks0,tp1), prefetch G2 -> A
        LOADC(c, 1, 0, bA0, bA1, bA2, bA3);
        COMPG(c, 0, 1, bB0, bB1, bB2, bB3);
        // G2: consume A (ks1,tp0), prefetch G3 -> B
        LOADC(c, 1, 1, bB0, bB1, bB2, bB3);
        COMPG(c, 1, 0, bA0, bA1, bA2, bA3);
        // G3: consume B (ks1,tp1), prefetch next chunk's G0 -> A (flies over MFMA+barrier)
        if (c < 15) LOADC(c + 1, 0, 0, bA0, bA1, bA2, bA3);
        COMPG(c, 1, 1, bB0, bB1, bB2, bB3);

        MFMA_STEP(c & 1, ah);
        __syncthreads();
    }

    // epilogue: v = sum_k W3[k]*relu(h2 + b2[k]) + b3; reduce over 16 lanes (k)
    float w3v[2][4], b2v[2][4];
#pragma unroll
    for (int th = 0; th < 2; ++th)
#pragma unroll
        for (int tn = 0; tn < 4; ++tn) {
            const int k = th * 64 + tn * 16 + l15;
            w3v[th][tn] = W3[k];
            b2v[th][tn] = b2[k];
        }
    const float b3v = b3[0];
#pragma unroll
    for (int tm = 0; tm < 4; ++tm)
#pragma unroll
        for (int r = 0; r < 4; ++r) {
            float v = 0.f;
#pragma unroll
            for (int th = 0; th < 2; ++th)
#pragma unroll
                for (int tn = 0; tn < 4; ++tn)
                    v = fmaf(w3v[th][tn], fmaxf(acc[tm][th][tn][r] + b2v[th][tn], 0.f), v);
            v += __shfl_xor(v, 1, 16);
            v += __shfl_xor(v, 2, 16);
            v += __shfl_xor(v, 4, 16);
            v += __shfl_xor(v, 8, 16);
            if (l15 == 0) {
                const int p = pairbase + tm * 16 + l4 * 4 + r;
                if (p < NPAIR) {
                    int i, j;
                    ptoij(p, i, j);
                    K[i * NN + j] = v + b3v;
                }
            }
        }
}

// ---------- fallback (R5 proven): in-loop exp2 sigmoid -------------------------
#define SIG_CHUNK(cc, dst)                                                   \
    {                                                                        \
        _Pragma("unroll")                                                    \
        for (int ks_ = 0; ks_ < 2; ++ks_) {                                  \
            const int m0_ = (cc) * 64 + ks_ * 32 + l4 * 8;                   \
            const f32x4 a0_ = *reinterpret_cast<const f32x4*>(&sa[m0_]);     \
            const f32x4 a1_ = *reinterpret_cast<const f32x4*>(&sa[m0_ + 4]); \
            const f32x4 c0_ = *reinterpret_cast<const f32x4*>(&sc[m0_]);     \
            const f32x4 c1_ = *reinterpret_cast<const f32x4*>(&sc[m0_ + 4]); \
            const f32x4 b0_ = *reinterpret_cast<const f32x4*>(&sb[m0_]);     \
            const f32x4 b1_ = *reinterpret_cast<const f32x4*>(&sb[m0_ + 4]); \
            _Pragma("unroll")                                                \
            for (int tm_ = 0; tm_ < 4; ++tm_) {                              \
                float s_[8];                                                 \
                _Pragma("unroll")                                            \
                for (int e_ = 0; e_ < 4; ++e_) {                             \
                    const float u0_ = fmaf(xia[tm_], a0_[e_], fmaf(xja[tm_], c0_[e_], b0_[e_])); \
                    const float u1_ = fmaf(xia[tm_], a1_[e_], fmaf(xja[tm_], c1_[e_], b1_[e_])); \
                    s_[e_]     = __builtin_amdgcn_rcpf(1.0f + __builtin_amdgcn_exp2f(u0_)); \
                    s_[e_ + 4] = __builtin_amdgcn_rcpf(1.0f + __builtin_amdgcn_exp2f(u1_)); \
                }                                                            \
                union { s16x8 v; uint u[4]; } fr_;                           \
                _Pragma("unroll")                                            \
                for (int h_ = 0; h_ < 4; ++h_) {                             \
                    b16x2 p_;                                                \
                    p_.x = (__bf16)s_[2 * h_];                               \
                    p_.y = (__bf16)s_[2 * h_ + 1];                           \
                    fr_.u[h_] = __builtin_bit_cast(uint, p_);                \
                }                                                            \
                dst[ks_][tm_] = fr_.v;                                       \
            }                                                                \
        }                                                                    \
    }

__global__ __launch_bounds__(256, 2) void mlp_pairs(
    const float* __restrict__ x,
    const float* __restrict__ W1, const float* __restrict__ b1,
    const ushort* __restrict__ WhiS,
    const float* __restrict__ b2, const float* __restrict__ W3,
    const float* __restrict__ b3, float* __restrict__ K)
{
    __shared__ __align__(16) float sa[MD], sc[MD], sb[MD];
    __shared__ __align__(16) ushort Wh[2][8192];

    const int t = threadIdx.x;
    const int lane = t & 63, wv = t >> 6;
    const int l15 = lane & 15, l4 = lane >> 4;

    const float NL2E = -1.4426950408889634f;
    for (int m = t; m < MD; m += 256) {
        const float2 w = reinterpret_cast<const float2*>(W1)[m];
        sa[m] = w.x * NL2E;
        sc[m] = w.y * NL2E;
        sb[m] = b1[m] * NL2E;
    }

    const int pairbase = blockIdx.x * 256 + wv * 64;

    float xia[4], xja[4];
#pragma unroll
    for (int tm = 0; tm < 4; ++tm) {
        const int p = pairbase + tm * 16 + l15;
        if (p < NPAIR) {
            int i, j;
            ptoij(p, i, j);
            xia[tm] = x[i];
            xja[tm] = x[j];
        } else {
            xia[tm] = 0.f;
            xja[tm] = 0.f;
        }
    }

    f32x4 acc[4][2][4];
#pragma unroll
    for (int a = 0; a < 4; ++a)
#pragma unroll
        for (int th = 0; th < 2; ++th)
#pragma unroll
            for (int b = 0; b < 4; ++b) acc[a][th][b] = (f32x4){0.f, 0.f, 0.f, 0.f};

    STAGE(0, 0);
    __syncthreads();

    s16x8 ah[2][4];
    for (int c = 0; c < 16; ++c) {
        if (c < 15) STAGE(c + 1, (c + 1) & 1);
        SIG_CHUNK(c, ah);
        MFMA_STEP(c & 1, ah);
        __syncthreads();
    }

    float w3v[2][4], b2v[2][4];
#pragma unroll
    for (int th = 0; th < 2; ++th)
#pragma unroll
        for (int tn = 0; tn < 4; ++tn) {
            const int k = th * 64 + tn * 16 + l15;
            w3v[th][tn] = W3[k];
            b2v[th][tn] = b2[k];
        }
    const float b3v = b3[0];
#pragma unroll
    for (int tm = 0; tm < 4; ++tm)
#pragma unroll
        for (int r = 0; r < 4; ++r) {
            float v = 0.f;
#pragma unroll
            for (int th = 0; th < 2; ++th)
#pragma unroll
                for (int tn = 0; tn < 4; ++tn)
                    v = fmaf(w3v[th][tn], fmaxf(acc[tm][th][tn][r] + b2v[th][tn], 0.f), v);
            v += __shfl_xor(v, 1, 16);
            v += __shfl_xor(v, 2, 16);
            v += __shfl_xor(v, 4, 16);
            v += __shfl_xor(v, 8, 16);
            if (l15 == 0) {
                const int p = pairbase + tm * 16 + l4 * 4 + r;
                if (p < NPAIR) {
                    int i, j;
                    ptoij(p, i, j);
                    K[i * NN + j] = v + b3v;
                }
            }
        }
}

// ---------------- Kernel 2: C = K^T K (768^3 fp32 GEMM) --------------------
__global__ __launch_bounds__(256) void ktk(const float* __restrict__ K,
                                           float* __restrict__ C)
{
    const int b0 = blockIdx.x * 64;
    const int a0 = blockIdx.y * 64;
    __shared__ float Ka[64][68];
    __shared__ float Kb[64][68];
    const int t  = threadIdx.x;
    const int tb = t & 15;
    const int ta = t >> 4;
    float acc[4][4];
#pragma unroll
    for (int u = 0; u < 4; u++)
#pragma unroll
        for (int v = 0; v < 4; v++) acc[u][v] = 0.f;
    const int kmax = (a0 < b0 ? a0 : b0) + 64;
    for (int k0 = 0; k0 < kmax; k0 += 64) {
#pragma unroll
        for (int q = 0; q < 4; q++) {
            const int f  = t + q * 256;
            const int kk = f >> 4;
            const int c4 = (f & 15) * 4;
            *reinterpret_cast<float4*>(&Ka[kk][c4]) =
                *reinterpret_cast<const float4*>(K + (k0 + kk) * NN + a0 + c4);
            *reinterpret_cast<float4*>(&Kb[kk][c4]) =
                *reinterpret_cast<const float4*>(K + (k0 + kk) * NN + b0 + c4);
        }
        __syncthreads();
#pragma unroll 8
        for (int kk = 0; kk < 64; kk++) {
            const float4 av = *reinterpret_cast<const float4*>(&Ka[kk][ta * 4]);
            const float4 bv = *reinterpret_cast<const float4*>(&Kb[kk][tb * 4]);
            const float a4[4] = {av.x, av.y, av.z, av.w};
            const float b4[4] = {bv.x, bv.y, bv.z, bv.w};
#pragma unroll
            for (int u = 0; u < 4; u++)
#pragma unroll
                for (int v = 0; v < 4; v++)
                    acc[u][v] = fmaf(a4[u], b4[v], acc[u][v]);
        }
        __syncthreads();
    }
#pragma unroll
    for (int u = 0; u < 4; u++) {
        float4 o;
        o.x = acc[u][0]; o.y = acc[u][1]; o.z = acc[u][2]; o.w = acc[u][3];
        *reinterpret_cast<float4*>(C + (a0 + ta * 4 + u) * NN + b0 + tb * 4) = o;
    }
}

extern "C" void kernel_launch(void* const* d_in, const int* in_sizes, int n_in,
                              void* d_out, int out_size, void* d_ws, size_t ws_size,
                              hipStream_t stream)
{
    const float* x  = (const float*)d_in[0];
    const float* W1 = (const float*)d_in[1];
    const float* b1 = (const float*)d_in[2];
    const float* W2 = (const float*)d_in[3];
    const float* b2 = (const float*)d_in[4];
    const float* W3 = (const float*)d_in[5];
    const float* b3 = (const float*)d_in[6];
    float* Kmat = (float*)d_ws;                       // 2,359,296 B
    float* C    = (float*)d_out;

    const size_t kBytes  = (size_t)NN * NN * sizeof(float);
    const size_t wBytes  = 262144;                    // W2 bf16 swizzled
    const size_t tBytes  = (size_t)NN * MD * sizeof(float);   // 3 MB per table
    const size_t needTab = kBytes + wBytes + 2 * tBytes;      // ~8.9 MB
    const size_t needR5  = kBytes + wBytes;                   // ~2.6 MB

    hipMemsetAsync(Kmat, 0, kBytes, stream);
    if (ws_size >= needTab) {
        ushort* WhiS = (ushort*)((char*)d_ws + kBytes);
        float*  EA   = (float*)((char*)d_ws + kBytes + wBytes);
        float*  EC   = EA + NN * MD;
        w2bf16<<<64, 256, 0, stream>>>(W2, WhiS);
        etab<<<NN, 256, 0, stream>>>(x, W1, b1, EA, EC);
        mlp_pairs3<<<NPBLK, 256, 0, stream>>>(EA, EC, WhiS, b2, W3, b3, Kmat);
    } else if (ws_size >= needR5) {
        ushort* WhiS = (ushort*)((char*)d_ws + kBytes);
        w2bf16<<<64, 256, 0, stream>>>(W2, WhiS);
        mlp_pairs<<<NPBLK, 256, 0, stream>>>(x, W1, b1, WhiS, b2, W3, b3, Kmat);
    }
    ktk<<<dim3(NN / 64, NN / 64), 256, 0, stream>>>(Kmat, C);
}

// Round 8
// 177.362 us; speedup vs baseline: 1.9318x; 1.8485x over previous
//
#include <hip/hip_runtime.h>
#include <hip/hip_bf16.h>

#define NN 768
#define MD 1024
#define NPAIR 295296            // 768*769/2
#define NPBLK2 2307             // NPAIR / 128 (exact)

typedef __attribute__((ext_vector_type(8))) short s16x8;
typedef __attribute__((ext_vector_type(4))) float f32x4;
typedef __attribute__((ext_vector_type(2))) __bf16 b16x2;

__device__ __forceinline__ ushort bf16_rn(float f) {
    uint u = __builtin_bit_cast(uint, f);
    u += 0x7FFFu + ((u >> 16) & 1u);
    return (ushort)(u >> 16);
}

// inverse triangular index: p -> (i,j), off(i) = i*(1537-i)/2, j = i + p - off(i)
__device__ __forceinline__ void ptoij(int p, int& io, int& jo) {
    const float disc = (float)(1537 * 1537 - 8 * p);
    int i = (int)((1537.0f - sqrtf(disc)) * 0.5f);
    i = i < 0 ? 0 : (i > 767 ? 767 : i);
    while (i > 0 && p < i * (1537 - i) / 2) --i;
    while (i < 767 && p >= (i + 1) * (1536 - i) / 2) ++i;
    io = i;
    jo = i + (p - i * (1537 - i) / 2);
}

#define GLOAD16(gsrc, ldst)                                                        \
    __builtin_amdgcn_global_load_lds(                                              \
        (const __attribute__((address_space(1))) void*)(gsrc),                     \
        (__attribute__((address_space(3))) void*)(ldst), 16, 0, 0)

// ---------- one-time: W2 -> bf16 (RNE), chunk-major + XOR-swizzled -------------
// chunk c (m0=c*64): 128 rows(k) x 128B; byte-in-row = (mloc8*16) ^ ((k&7)<<4)
__global__ __launch_bounds__(256) void w2bf16(const float* __restrict__ W2,
                                              ushort* __restrict__ WhiS)
{
    const int id = blockIdx.x * 256 + threadIdx.x;
    const int k = id >> 7;
    const int m = (id & 127) * 8;
    const float4 a = *reinterpret_cast<const float4*>(W2 + k * MD + m);
    const float4 b = *reinterpret_cast<const float4*>(W2 + k * MD + m + 4);
    const float w[8] = {a.x, a.y, a.z, a.w, b.x, b.y, b.z, b.w};
    s16x8 h;
#pragma unroll
    for (int e = 0; e < 8; ++e) h[e] = (short)bf16_rn(w[e]);
    const int c = m >> 6;
    const int mloc8 = (m >> 3) & 7;
    const int byte = (mloc8 * 16) ^ ((k & 7) << 4);
    const int off = c * 8192 + ((k * 128 + byte) >> 1);
    *reinterpret_cast<s16x8*>(&WhiS[off]) = h;
}

// ---- macros (ambient locals) ---------------------------------------------------
#define STAGE(cc, buf)                                                       \
    {                                                                        \
        const ushort* sh_ = WhiS + (cc) * 8192;                              \
        _Pragma("unroll")                                                    \
        for (int q_ = 0; q_ < 4; ++q_) {                                     \
            const int off_ = (wv * 4 + q_) * 512;                            \
            GLOAD16(sh_ + off_ + lane * 8, &Wh[buf][off_]);                  \
        }                                                                    \
    }

// weights in sa/sc/sb pre-scaled by -log2(e): sigma = rcp(1 + 2^u)
#define SIG_CHUNK(cc, dst, TMN)                                              \
    {                                                                        \
        _Pragma("unroll")                                                    \
        for (int ks_ = 0; ks_ < 2; ++ks_) {                                  \
            const int m0_ = (cc) * 64 + ks_ * 32 + l4 * 8;                   \
            const f32x4 a0_ = *reinterpret_cast<const f32x4*>(&sa[m0_]);     \
            const f32x4 a1_ = *reinterpret_cast<const f32x4*>(&sa[m0_ + 4]); \
            const f32x4 c0_ = *reinterpret_cast<const f32x4*>(&sc[m0_]);     \
            const f32x4 c1_ = *reinterpret_cast<const f32x4*>(&sc[m0_ + 4]); \
            const f32x4 b0_ = *reinterpret_cast<const f32x4*>(&sb[m0_]);     \
            const f32x4 b1_ = *reinterpret_cast<const f32x4*>(&sb[m0_ + 4]); \
            _Pragma("unroll")                                                \
            for (int tm_ = 0; tm_ < (TMN); ++tm_) {                          \
                float s_[8];                                                 \
                _Pragma("unroll")                                            \
                for (int e_ = 0; e_ < 4; ++e_) {                             \
                    const float u0_ = fmaf(xia[tm_], a0_[e_], fmaf(xja[tm_], c0_[e_], b0_[e_])); \
                    const float u1_ = fmaf(xia[tm_], a1_[e_], fmaf(xja[tm_], c1_[e_], b1_[e_])); \
                    s_[e_]     = __builtin_amdgcn_rcpf(1.0f + __builtin_amdgcn_exp2f(u0_)); \
                    s_[e_ + 4] = __builtin_amdgcn_rcpf(1.0f + __builtin_amdgcn_exp2f(u1_)); \
                }                                                            \
                union { s16x8 v; uint u[4]; } fr_;                           \
                _Pragma("unroll")                                            \
                for (int h_ = 0; h_ < 4; ++h_) {                             \
                    b16x2 p_;                                                \
                    p_.x = (__bf16)s_[2 * h_];                               \
                    p_.y = (__bf16)s_[2 * h_ + 1];                           \
                    fr_.u[h_] = __builtin_bit_cast(uint, p_);                \
                }                                                            \
                dst[ks_][tm_] = fr_.v;                                       \
            }                                                                \
        }                                                                    \
    }

#define MFMA_STEP(buf, src, TMN)                                             \
    {                                                                        \
        _Pragma("unroll")                                                    \
        for (int ks_ = 0; ks_ < 2; ++ks_) {                                  \
            _Pragma("unroll")                                                \
            for (int th_ = 0; th_ < 2; ++th_) {                              \
                s16x8 bh_[4];                                                \
                _Pragma("unroll")                                            \
                for (int tn_ = 0; tn_ < 4; ++tn_) {                          \
                    const int k_ = th_ * 64 + tn_ * 16 + l15;                \
                    const int byte_ = (ks_ * 64 + l4 * 16) ^ ((k_ & 7) << 4);\
                    const int idx_ = (k_ * 128 + byte_) >> 1;                \
                    bh_[tn_] = *reinterpret_cast<const s16x8*>(&Wh[buf][idx_]); \
                }                                                            \
                __builtin_amdgcn_s_setprio(1);                               \
                _Pragma("unroll")                                            \
                for (int tm_ = 0; tm_ < (TMN); ++tm_)                        \
                    _Pragma("unroll")                                        \
                    for (int tn_ = 0; tn_ < 4; ++tn_)                        \
                        acc[tm_][th_][tn_] = __builtin_amdgcn_mfma_f32_16x16x32_bf16( \
                            src[ks_][tm_], bh_[tn_], acc[tm_][th_][tn_], 0, 0, 0);    \
                __builtin_amdgcn_s_setprio(0);                               \
            }                                                                \
        }                                                                    \
    }

// ---------- main: 32 pairs x 128 k per wave, 3 waves/SIMD ----------------------
__global__ __launch_bounds__(256, 3) void mlp_pairs(
    const float* __restrict__ x,
    const float* __restrict__ W1, const float* __restrict__ b1,
    const ushort* __restrict__ WhiS,
    const float* __restrict__ b2, const float* __restrict__ W3,
    const float* __restrict__ b3, float* __restrict__ K)
{
    __shared__ __align__(16) float sa[MD], sc[MD], sb[MD];
    __shared__ __align__(16) ushort Wh[2][8192];

    const int t = threadIdx.x;
    const int lane = t & 63, wv = t >> 6;
    const int l15 = lane & 15, l4 = lane >> 4;

    const float NL2E = -1.4426950408889634f;
    for (int m = t; m < MD; m += 256) {
        const float2 w = reinterpret_cast<const float2*>(W1)[m];
        sa[m] = w.x * NL2E;
        sc[m] = w.y * NL2E;
        sb[m] = b1[m] * NL2E;
    }

    const int pairbase = blockIdx.x * 128 + wv * 32;

    float xia[2], xja[2];
#pragma unroll
    for (int tm = 0; tm < 2; ++tm) {
        const int p = pairbase + tm * 16 + l15;
        if (p < NPAIR) {
            int i, j;
            ptoij(p, i, j);
            xia[tm] = x[i];
            xja[tm] = x[j];
        } else {
            xia[tm] = 0.f;
            xja[tm] = 0.f;
        }
    }

    f32x4 acc[2][2][4];
#pragma unroll
    for (int a = 0; a < 2; ++a)
#pragma unroll
        for (int th = 0; th < 2; ++th)
#pragma unroll
            for (int b = 0; b < 4; ++b) acc[a][th][b] = (f32x4){0.f, 0.f, 0.f, 0.f};

    STAGE(0, 0);
    __syncthreads();                 // sa/sc/sb written AND Wh[0] staged

    s16x8 ah[2][2];
    for (int c = 0; c < 16; ++c) {
        if (c < 15) STAGE(c + 1, (c + 1) & 1);   // async into other buffer
        SIG_CHUNK(c, ah, 2);                     // VALU while loads fly
        MFMA_STEP(c & 1, ah, 2);
        __syncthreads();             // next buf ready; all reads of cur buf done
    }

    // epilogue: v = sum_k W3[k]*relu(h2 + b2[k]) + b3; reduce over 16 lanes (k)
    float w3v[2][4], b2v[2][4];
#pragma unroll
    for (int th = 0; th < 2; ++th)
#pragma unroll
        for (int tn = 0; tn < 4; ++tn) {
            const int k = th * 64 + tn * 16 + l15;
            w3v[th][tn] = W3[k];
            b2v[th][tn] = b2[k];
        }
    const float b3v = b3[0];
#pragma unroll
    for (int tm = 0; tm < 2; ++tm)
#pragma unroll
        for (int r = 0; r < 4; ++r) {
            float v = 0.f;
#pragma unroll
            for (int th = 0; th < 2; ++th)
#pragma unroll
                for (int tn = 0; tn < 4; ++tn)
                    v = fmaf(w3v[th][tn], fmaxf(acc[tm][th][tn][r] + b2v[th][tn], 0.f), v);
            v += __shfl_xor(v, 1, 16);
            v += __shfl_xor(v, 2, 16);
            v += __shfl_xor(v, 4, 16);
            v += __shfl_xor(v, 8, 16);
            if (l15 == 0) {
                const int p = pairbase + tm * 16 + l4 * 4 + r;
                if (p < NPAIR) {
                    int i, j;
                    ptoij(p, i, j);
                    K[i * NN + j] = v + b3v;
                }
            }
        }
}

// ---------- fallback fp32 MLP kernel (only if ws too small; never expected) ----
#define MC 32
#define JT 128
#define SPAD 132
__global__ __launch_bounds__(256) void mlp_fill(
    const float* __restrict__ x,
    const float* __restrict__ W1, const float* __restrict__ b1,
    const float* __restrict__ W2, const float* __restrict__ b2,
    const float* __restrict__ W3, const float* __restrict__ b3,
    float* __restrict__ K)
{
    const int i  = blockIdx.y;
    const int j0 = blockIdx.x * JT;
    if (j0 + JT - 1 < i) return;
    __shared__ float sA[MD];
    __shared__ float sCw[MD];
    __shared__ float sxj[JT];
    __shared__ float S[MC][SPAD];
    __shared__ float W2t[MC][SPAD];
    const int t = threadIdx.x;
    const float xi = x[i];
    for (int m = t; m < MD; m += 256) {
        const float2 w = reinterpret_cast<const float2*>(W1)[m];
        sA[m]  = fmaf(xi, w.x, b1[m]);
        sCw[m] = w.y;
    }
    if (t < JT) sxj[t] = x[j0 + t];
    const int tk = t & 15;
    const int tj = t >> 4;
    float w3r[8], b2r[8];
#pragma unroll
    for (int kk = 0; kk < 8; kk++) {
        w3r[kk] = W3[tk * 8 + kk];
        b2r[kk] = b2[tk * 8 + kk];
    }
    float acc[8][8];
#pragma unroll
    for (int jj = 0; jj < 8; jj++)
#pragma unroll
        for (int kk = 0; kk < 8; kk++) acc[jj][kk] = 0.f;
    const int jx   = t & 127;
    const int mseg = (t >> 7) * 16;
    __syncthreads();
    const float xjv = sxj[jx];
    for (int m0 = 0; m0 < MD; m0 += MC) {
#pragma unroll
        for (int q = 0; q < 4; q++) {
            const int f   = t + q * 256;
            const int k   = f >> 3;
            const int mm4 = (f & 7) * 4;
            const float4 w = *reinterpret_cast<const float4*>(W2 + k * MD + m0 + mm4);
            W2t[mm4 + 0][k] = w.x;
            W2t[mm4 + 1][k] = w.y;
            W2t[mm4 + 2][k] = w.z;
            W2t[mm4 + 3][k] = w.w;
        }
#pragma unroll
        for (int q = 0; q < 16; q++) {
            const int ml = mseg + q;
            const float z = fmaf(xjv, sCw[m0 + ml], sA[m0 + ml]);
            S[ml][jx] = 1.0f / (1.0f + __expf(-z));
        }
        __syncthreads();
#pragma unroll 4
        for (int mm = 0; mm < MC; mm++) {
            const float4 s0 = *reinterpret_cast<const float4*>(&S[mm][tj * 8]);
            const float4 s1 = *reinterpret_cast<const float4*>(&S[mm][tj * 8 + 4]);
            const float4 w0 = *reinterpret_cast<const float4*>(&W2t[mm][tk * 8]);
            const float4 w1 = *reinterpret_cast<const float4*>(&W2t[mm][tk * 8 + 4]);
            const float sj[8] = {s0.x, s0.y, s0.z, s0.w, s1.x, s1.y, s1.z, s1.w};
            const float wk[8] = {w0.x, w0.y, w0.z, w0.w, w1.x, w1.y, w1.z, w1.w};
#pragma unroll
            for (int jj = 0; jj < 8; jj++)
#pragma unroll
                for (int kk = 0; kk < 8; kk++)
                    acc[jj][kk] = fmaf(sj[jj], wk[kk], acc[jj][kk]);
        }
        __syncthreads();
    }
    const float b3v = b3[0];
#pragma unroll
    for (int jj = 0; jj < 8; jj++) {
        float v = 0.f;
#pragma unroll
        for (int kk = 0; kk < 8; kk++) {
            const float h = acc[jj][kk] + b2r[kk];
            v = fmaf(w3r[kk], fmaxf(h, 0.f), v);
        }
#pragma unroll
        for (int off = 8; off >= 1; off >>= 1)
            v += __shfl_xor(v, off, 16);
        if (tk == 0) {
            const int j = j0 + tj * 8 + jj;
            if (j >= i) K[i * NN + j] = v + b3v;
        }
    }
}

// ---------------- Kernel 2: C = K^T K (768^3 fp32 GEMM) --------------------
__global__ __launch_bounds__(256) void ktk(const float* __restrict__ K,
                                           float* __restrict__ C)
{
    const int b0 = blockIdx.x * 64;
    const int a0 = blockIdx.y * 64;
    __shared__ float Ka[64][68];
    __shared__ float Kb[64][68];
    const int t  = threadIdx.x;
    const int tb = t & 15;
    const int ta = t >> 4;
    float acc[4][4];
#pragma unroll
    for (int u = 0; u < 4; u++)
#pragma unroll
        for (int v = 0; v < 4; v++) acc[u][v] = 0.f;
    const int kmax = (a0 < b0 ? a0 : b0) + 64;
    for (int k0 = 0; k0 < kmax; k0 += 64) {
#pragma unroll
        for (int q = 0; q < 4; q++) {
            const int f  = t + q * 256;
            const int kk = f >> 4;
            const int c4 = (f & 15) * 4;
            *reinterpret_cast<float4*>(&Ka[kk][c4]) =
                *reinterpret_cast<const float4*>(K + (k0 + kk) * NN + a0 + c4);
            *reinterpret_cast<float4*>(&Kb[kk][c4]) =
                *reinterpret_cast<const float4*>(K + (k0 + kk) * NN + b0 + c4);
        }
        __syncthreads();
#pragma unroll 8
        for (int kk = 0; kk < 64; kk++) {
            const float4 av = *reinterpret_cast<const float4*>(&Ka[kk][ta * 4]);
            const float4 bv = *reinterpret_cast<const float4*>(&Kb[kk][tb * 4]);
            const float a4[4] = {av.x, av.y, av.z, av.w};
            const float b4[4] = {bv.x, bv.y, bv.z, bv.w};
#pragma unroll
            for (int u = 0; u < 4; u++)
#pragma unroll
                for (int v = 0; v < 4; v++)
                    acc[u][v] = fmaf(a4[u], b4[v], acc[u][v]);
        }
        __syncthreads();
    }
#pragma unroll
    for (int u = 0; u < 4; u++) {
        float4 o;
        o.x = acc[u][0]; o.y = acc[u][1]; o.z = acc[u][2]; o.w = acc[u][3];
        *reinterpret_cast<float4*>(C + (a0 + ta * 4 + u) * NN + b0 + tb * 4) = o;
    }
}

extern "C" void kernel_launch(void* const* d_in, const int* in_sizes, int n_in,
                              void* d_out, int out_size, void* d_ws, size_t ws_size,
                              hipStream_t stream)
{
    const float* x  = (const float*)d_in[0];
    const float* W1 = (const float*)d_in[1];
    const float* b1 = (const float*)d_in[2];
    const float* W2 = (const float*)d_in[3];
    const float* b2 = (const float*)d_in[4];
    const float* W3 = (const float*)d_in[5];
    const float* b3 = (const float*)d_in[6];
    float* Kmat = (float*)d_ws;                       // 2,359,296 B
    float* C    = (float*)d_out;

    const size_t kBytes = (size_t)NN * NN * sizeof(float);
    const size_t need   = kBytes + 262144;            // + W2 bf16 swizzled

    hipMemsetAsync(Kmat, 0, kBytes, stream);
    if (ws_size >= need) {
        ushort* WhiS = (ushort*)((char*)d_ws + kBytes);
        w2bf16<<<64, 256, 0, stream>>>(W2, WhiS);
        mlp_pairs<<<NPBLK2, 256, 0, stream>>>(x, W1, b1, WhiS, b2, W3, b3, Kmat);
    } else {
        mlp_fill<<<dim3(6, NN), 256, 0, stream>>>(x, W1, b1, W2, b2, W3, b3, Kmat);
    }
    ktk<<<dim3(NN / 64, NN / 64), 256, 0, stream>>>(Kmat, C);
}